// Round 1
// baseline (103.025 us; speedup 1.0000x reference)
//
#include <hip/hip_runtime.h>

// ---------------------------------------------------------------------------
// PodNetClassifier: out[b][c] = sum_k simi*softmax_k(simi),
//   simi[b,c,k] = -max(2 - 2*dot(a_b, th_{c*10+k}), 0),
//   a = l2norm(x rows), th[j=c*10+kk][d] = l2norm_over_d(theta[d][kk][c])
// B=8192, D=64, K=10, C=1000.
// ---------------------------------------------------------------------------

#define BATCH     8192
#define DIM       64
#define KPROX     10
#define NCLASS    1000
#define NCOL      (NCLASS * KPROX)   // 10000

#define BM        64                 // rows per block (4 waves x 16)
#define BN        80                 // cols per block = 8 classes
#define NTILE     5                  // 16-wide MFMA col tiles per block
#define GCLS      8                  // classes per block
#define NBLK_N    (NCOL / BN)        // 125
#define NBLK_M    (BATCH / BM)       // 128

typedef __attribute__((ext_vector_type(8))) short bf16x8;
typedef __attribute__((ext_vector_type(4))) float f32x4;

__device__ inline unsigned short f32_to_bf16(float f) {
    unsigned int u = __float_as_uint(f);
    u += 0x7FFFu + ((u >> 16) & 1u);   // round-to-nearest-even
    return (unsigned short)(u >> 16);
}

// ---- kernel 1: normalize x rows -> bf16 A[8192][64], one wave per row ------
__global__ void norm_x_kernel(const float* __restrict__ x,
                              unsigned short* __restrict__ A) {
    int wave = threadIdx.x >> 6;
    int lane = threadIdx.x & 63;
    int row  = blockIdx.x * 4 + wave;
    float v  = x[row * DIM + lane];
    float ss = v * v;
    #pragma unroll
    for (int off = 32; off >= 1; off >>= 1)
        ss += __shfl_xor(ss, off);
    float scale = 1.0f / fmaxf(sqrtf(ss), 1e-12f);
    A[row * DIM + lane] = f32_to_bf16(v * scale);
}

// ---- kernel 2: normalize theta -> bf16 TH[10000][64], thread per proxy -----
// j = c*10 + kk ; source theta[d][kk][c] at d*10000 + kk*1000 + c
__global__ void norm_th_kernel(const float* __restrict__ theta,
                               unsigned short* __restrict__ TH) {
    int tid = blockIdx.x * blockDim.x + threadIdx.x;
    if (tid >= NCOL) return;
    int c  = tid % NCLASS;           // consecutive threads -> consecutive c (coalesced reads)
    int kk = tid / NCLASS;
    const float* src = theta + kk * NCLASS + c;
    float v[DIM];
    float ss = 0.f;
    #pragma unroll
    for (int d = 0; d < DIM; ++d) {
        v[d] = src[(size_t)d * NCOL];
        ss += v[d] * v[d];
    }
    float scale = 1.0f / fmaxf(sqrtf(ss), 1e-12f);
    int j = c * KPROX + kk;
    unsigned short* dst = TH + (size_t)j * DIM;
    #pragma unroll
    for (int d = 0; d < DIM; ++d)
        dst[d] = f32_to_bf16(v[d] * scale);
}

// ---- main kernel: GEMM (MFMA bf16) + fused softmax-over-10 -----------------
__global__ __launch_bounds__(256)
void podnet_main_kernel(const unsigned short* __restrict__ A,
                        const unsigned short* __restrict__ TH,
                        float* __restrict__ out) {
    __shared__ float S[BM][BN + 4];   // +4 pad: breaks 4-way write conflict

    int bid = blockIdx.x;
    int bm  = bid / NBLK_N;           // consecutive blocks reuse the A tile
    int bn  = bid % NBLK_N;
    int m0  = bm * BM;
    int n0  = bn * BN;

    int wave = threadIdx.x >> 6;
    int lane = threadIdx.x & 63;
    int r16  = lane & 15;
    int hi   = lane >> 4;             // 0..3

    // A fragments: row = lane&15, k = hi*8 + i (+32 for second K-step).
    int arow = m0 + wave * 16 + r16;
    bf16x8 a0 = *(const bf16x8*)(A + (size_t)arow * DIM + hi * 8);
    bf16x8 a1 = *(const bf16x8*)(A + (size_t)arow * DIM + 32 + hi * 8);

    f32x4 acc[NTILE];
    #pragma unroll
    for (int t = 0; t < NTILE; ++t) {
        int brow = n0 + t * 16 + r16;
        bf16x8 b0 = *(const bf16x8*)(TH + (size_t)brow * DIM + hi * 8);
        bf16x8 b1 = *(const bf16x8*)(TH + (size_t)brow * DIM + 32 + hi * 8);
        f32x4 c = {0.f, 0.f, 0.f, 0.f};
        c = __builtin_amdgcn_mfma_f32_16x16x32_bf16(a0, b0, c, 0, 0, 0);
        c = __builtin_amdgcn_mfma_f32_16x16x32_bf16(a1, b1, c, 0, 0, 0);
        acc[t] = c;
    }

    // scores -> LDS (C/D layout: col = lane&15, row = hi*4 + reg)
    #pragma unroll
    for (int t = 0; t < NTILE; ++t) {
        int col = t * 16 + r16;
        #pragma unroll
        for (int r = 0; r < 4; ++r) {
            int row = wave * 16 + hi * 4 + r;
            float s = acc[t][r];
            S[row][col] = fminf(2.f * s - 2.f, 0.f);   // simi = -max(2-2s, 0)
        }
    }
    __syncthreads();

    // softmax over groups of 10: 64 rows x 8 classes = 512 pairs, 2/thread
    #pragma unroll
    for (int it = 0; it < 2; ++it) {
        int p   = threadIdx.x + it * 256;
        int row = p >> 3;
        int g   = p & 7;
        float sv[KPROX];
        float m = -1e30f;
        #pragma unroll
        for (int i = 0; i < KPROX; ++i) {
            sv[i] = S[row][g * KPROX + i];
            m = fmaxf(m, sv[i]);
        }
        float psum = 0.f, wsum = 0.f;
        #pragma unroll
        for (int i = 0; i < KPROX; ++i) {
            float e = __expf(sv[i] - m);
            psum += e;
            wsum += sv[i] * e;
        }
        out[(size_t)(m0 + row) * NCLASS + bn * GCLS + g] = wsum / psum;
    }
}

extern "C" void kernel_launch(void* const* d_in, const int* in_sizes, int n_in,
                              void* d_out, int out_size, void* d_ws, size_t ws_size,
                              hipStream_t stream) {
    const float* x     = (const float*)d_in[0];   // (8192, 64)
    const float* theta = (const float*)d_in[1];   // (64, 10, 1000)
    float* out = (float*)d_out;                   // (8192, 1000) f32

    unsigned short* A  = (unsigned short*)d_ws;                         // 1.0 MB
    unsigned short* TH = (unsigned short*)((char*)d_ws + (size_t)BATCH * DIM * 2); // 1.25 MB

    norm_x_kernel<<<BATCH / 4, 256, 0, stream>>>(x, A);
    norm_th_kernel<<<(NCOL + 255) / 256, 256, 0, stream>>>(theta, TH);
    podnet_main_kernel<<<NBLK_M * NBLK_N, 256, 0, stream>>>(A, TH, out);
}

// Round 2
// 101.605 us; speedup vs baseline: 1.0140x; 1.0140x over previous
//
#include <hip/hip_runtime.h>

// ---------------------------------------------------------------------------
// PodNetClassifier: out[b][c] = sum_k simi*softmax_k(simi),
//   simi[b,c,k] = -max(2 - 2*dot(a_b, th_{c*10+k}), 0)  (unit vectors => d2=2-2s)
// B=8192, D=64, K=10, C=1000.
// Round 2: no __syncthreads (wave-private LDS), pipelined B loads, no max-pass
// in softmax (simi in [-4,0]), float2 LDS reads + nontemporal float2 stores,
// LDS stride 82 (conflict-free score writes, 4-way reads).
// ---------------------------------------------------------------------------

#define BATCH     8192
#define DIM       64
#define KPROX     10
#define NCLASS    1000
#define NCOL      (NCLASS * KPROX)   // 10000

#define BM        64                 // rows per block (4 waves x 16)
#define BN        80                 // cols per block = 8 classes
#define NTILE     5                  // 16-wide MFMA col tiles per wave
#define GCLS      8                  // classes per block
#define NBLK_N    (NCOL / BN)        // 125
#define NBLK_M    (BATCH / BM)       // 128
#define SSTRIDE   82                 // LDS row stride (f32 words)

typedef __attribute__((ext_vector_type(8))) short bf16x8;
typedef __attribute__((ext_vector_type(4))) float f32x4;
typedef __attribute__((ext_vector_type(2))) float f32x2;

__device__ inline unsigned short f32_to_bf16(float f) {
    unsigned int u = __float_as_uint(f);
    u += 0x7FFFu + ((u >> 16) & 1u);   // round-to-nearest-even
    return (unsigned short)(u >> 16);
}

// ---- kernel 1: normalize x rows -> bf16 A[8192][64], one wave per row ------
__global__ void norm_x_kernel(const float* __restrict__ x,
                              unsigned short* __restrict__ A) {
    int wave = threadIdx.x >> 6;
    int lane = threadIdx.x & 63;
    int row  = blockIdx.x * 4 + wave;
    float v  = x[row * DIM + lane];
    float ss = v * v;
    #pragma unroll
    for (int off = 32; off >= 1; off >>= 1)
        ss += __shfl_xor(ss, off);
    float scale = 1.0f / fmaxf(sqrtf(ss), 1e-12f);
    A[row * DIM + lane] = f32_to_bf16(v * scale);
}

// ---- kernel 2: normalize theta -> bf16 TH[10000][64], thread per proxy -----
// j = c*10 + kk ; source theta[d][kk][c] at d*10000 + kk*1000 + c
__global__ void norm_th_kernel(const float* __restrict__ theta,
                               unsigned short* __restrict__ TH) {
    int tid = blockIdx.x * blockDim.x + threadIdx.x;
    if (tid >= NCOL) return;
    int c  = tid % NCLASS;           // consecutive threads -> consecutive c
    int kk = tid / NCLASS;
    const float* src = theta + kk * NCLASS + c;
    float v[DIM];
    float ss = 0.f;
    #pragma unroll
    for (int d = 0; d < DIM; ++d) {
        v[d] = src[(size_t)d * NCOL];
        ss += v[d] * v[d];
    }
    float scale = 1.0f / fmaxf(sqrtf(ss), 1e-12f);
    int j = c * KPROX + kk;
    unsigned short* dst = TH + (size_t)j * DIM;
    #pragma unroll
    for (int d = 0; d < DIM; ++d)
        dst[d] = f32_to_bf16(v[d] * scale);
}

// ---- main kernel: GEMM (MFMA bf16) + fused softmax-over-10, no barrier -----
__global__ __launch_bounds__(256)
void podnet_main_kernel(const unsigned short* __restrict__ A,
                        const unsigned short* __restrict__ TH,
                        float* __restrict__ out) {
    __shared__ float S[4][16][SSTRIDE];   // wave-private partitions

    int bid = blockIdx.x;
    int bm  = bid / NBLK_N;               // consecutive blocks reuse the A tile
    int bn  = bid % NBLK_N;
    int m0  = bm * BM;
    int n0  = bn * BN;

    int wave = threadIdx.x >> 6;
    int lane = threadIdx.x & 63;
    int r16  = lane & 15;
    int hi   = lane >> 4;                 // 0..3

    // A fragments: row = lane&15, k = hi*8 + i (+32 for second K-step)
    const unsigned short* ap = A + (size_t)(m0 + wave * 16 + r16) * DIM + hi * 8;
    bf16x8 a0 = *(const bf16x8*)ap;
    bf16x8 a1 = *(const bf16x8*)(ap + 32);

    // B fragments, 2-stage software pipeline over the 5 col tiles
    const unsigned short* bbase = TH + (size_t)(n0 + r16) * DIM + hi * 8;
    bf16x8 bc0 = *(const bf16x8*)bbase;
    bf16x8 bc1 = *(const bf16x8*)(bbase + 32);

    f32x4 acc[NTILE];
    #pragma unroll
    for (int t = 0; t < NTILE; ++t) {
        bf16x8 bnx0, bnx1;
        bool more = (t + 1 < NTILE);
        if (more) {
            const unsigned short* nb = bbase + (size_t)(t + 1) * 16 * DIM;
            bnx0 = *(const bf16x8*)nb;
            bnx1 = *(const bf16x8*)(nb + 32);
        }
        f32x4 c = {0.f, 0.f, 0.f, 0.f};
        c = __builtin_amdgcn_mfma_f32_16x16x32_bf16(a0, bc0, c, 0, 0, 0);
        c = __builtin_amdgcn_mfma_f32_16x16x32_bf16(a1, bc1, c, 0, 0, 0);
        acc[t] = c;
        if (more) { bc0 = bnx0; bc1 = bnx1; }
    }

    // scores -> wave-private LDS (C/D layout: col = lane&15, row = hi*4 + reg)
    // stride 82: write banks for hi=0..3 land at +0/+8/+16/+24 -> conflict-free
    #pragma unroll
    for (int t = 0; t < NTILE; ++t) {
        #pragma unroll
        for (int r = 0; r < 4; ++r) {
            S[wave][hi * 4 + r][t * 16 + r16] = fminf(2.f * acc[t][r] - 2.f, 0.f);
        }
    }
    // no __syncthreads: same-wave ds_write -> ds_read, lgkmcnt ordering suffices

    // softmax over groups of 10: each thread: 1 row, 2 adjacent classes
    int rr = lane >> 2;                   // 0..15
    int pp = lane & 3;                    // class pair 0..3
    const float* Srow = &S[wave][rr][0];
    f32x2 res;
    #pragma unroll
    for (int c2 = 0; c2 < 2; ++c2) {
        int col0 = (2 * pp + c2) * KPROX;
        float ps = 0.f, ws = 0.f;
        #pragma unroll
        for (int i = 0; i < 5; ++i) {
            f32x2 v = *(const f32x2*)(Srow + col0 + 2 * i);
            float e0 = __expf(v.x);       // simi in [-4,0] -> exp safe, no max
            float e1 = __expf(v.y);
            ps += e0 + e1;
            ws = fmaf(v.x, e0, fmaf(v.y, e1, ws));
        }
        res[c2] = ws / ps;
    }
    float* op = out + (size_t)(m0 + wave * 16 + rr) * NCLASS + bn * GCLS + 2 * pp;
    __builtin_nontemporal_store(res, (f32x2*)op);
}

extern "C" void kernel_launch(void* const* d_in, const int* in_sizes, int n_in,
                              void* d_out, int out_size, void* d_ws, size_t ws_size,
                              hipStream_t stream) {
    const float* x     = (const float*)d_in[0];   // (8192, 64)
    const float* theta = (const float*)d_in[1];   // (64, 10, 1000)
    float* out = (float*)d_out;                   // (8192, 1000) f32

    unsigned short* A  = (unsigned short*)d_ws;                                    // 1.0 MB
    unsigned short* TH = (unsigned short*)((char*)d_ws + (size_t)BATCH * DIM * 2); // 1.25 MB

    norm_x_kernel<<<BATCH / 4, 256, 0, stream>>>(x, A);
    norm_th_kernel<<<(NCOL + 255) / 256, 256, 0, stream>>>(theta, TH);
    podnet_main_kernel<<<NBLK_M * NBLK_N, 256, 0, stream>>>(A, TH, out);
}

// Round 3
// 42.636 us; speedup vs baseline: 2.4164x; 2.3831x over previous
//
#include <hip/hip_runtime.h>

// ---------------------------------------------------------------------------
// PodNetClassifier: out[b][c] = sum_k simi*softmax_k(simi),
//   simi[b,c,k] = -max(2 - 2*dot(a_b, th_{c*10+k}), 0)  (unit vectors)
// Round 3: fragment-ready packed operand planes (all loads coalesced dwordx4,
// all independent), 32x80 wave tiles, conflict-free col-major LDS epilogue
// (b128 writes / b64 reads), no barriers.
// ---------------------------------------------------------------------------

#define BATCH   8192
#define DIM     64
#define KPROX   10
#define NCLASS  1000
#define NCOL    (NCLASS * KPROX)   // 10000
#define NBTILE  (BATCH / 16)       // 512
#define NNTILE  (NCOL / 16)        // 625

#define BM      128                // rows per block (4 waves x 32)
#define BN      80                 // cols per block (5 mfma tiles, 8 classes)
#define NBM     (BATCH / BM)       // 64
#define NBN     (NCOL / BN)        // 125
#define CSTR    20                 // LDS words per column slab (16 rows + pad)

typedef __attribute__((ext_vector_type(8))) short bf16x8;
typedef __attribute__((ext_vector_type(4))) float f32x4;
typedef __attribute__((ext_vector_type(2))) float f32x2;

__device__ inline unsigned short f32_to_bf16(float f) {
    unsigned int u = __float_as_uint(f);
    u += 0x7FFFu + ((u >> 16) & 1u);   // round-to-nearest-even
    return (unsigned short)(u >> 16);
}

// ---- X: fused L2-normalize + fragment pack; one wave per 16-row tile -------
// Plane layout: Xf_p[(btile*64 + lane)*8 + i] = a[btile*16 + (lane&15)][p*32 + (lane>>4)*8 + i]
__global__ __launch_bounds__(256)
void norm_pack_x(const float* __restrict__ x,
                 unsigned short* __restrict__ Xf0,
                 unsigned short* __restrict__ Xf1) {
    int wave = threadIdx.x >> 6, lane = threadIdx.x & 63;
    int bt  = blockIdx.x * 4 + wave;
    int r16 = lane & 15, hi = lane >> 4;
    const float* src = x + (size_t)(bt * 16 + r16) * DIM + hi * 8;
    f32x4 v0 = *(const f32x4*)(src);
    f32x4 v1 = *(const f32x4*)(src + 4);
    f32x4 v2 = *(const f32x4*)(src + 32);
    f32x4 v3 = *(const f32x4*)(src + 36);
    float ss = 0.f;
    #pragma unroll
    for (int i = 0; i < 4; ++i)
        ss += v0[i]*v0[i] + v1[i]*v1[i] + v2[i]*v2[i] + v3[i]*v3[i];
    ss += __shfl_xor(ss, 16);          // combine the 4 hi-groups of this row
    ss += __shfl_xor(ss, 32);
    float sc = 1.0f / fmaxf(sqrtf(ss), 1e-12f);
    bf16x8 p0, p1;
    #pragma unroll
    for (int i = 0; i < 4; ++i) {
        p0[i]     = (short)f32_to_bf16(v0[i] * sc);
        p0[i + 4] = (short)f32_to_bf16(v1[i] * sc);
        p1[i]     = (short)f32_to_bf16(v2[i] * sc);
        p1[i + 4] = (short)f32_to_bf16(v3[i] * sc);
    }
    ((bf16x8*)Xf0)[bt * 64 + lane] = p0;
    ((bf16x8*)Xf1)[bt * 64 + lane] = p1;
}

// ---- TH: normalize proxy j = c*10+kk over d, write fragment planes ---------
__global__ void norm_pack_th(const float* __restrict__ theta,
                             unsigned short* __restrict__ THf0,
                             unsigned short* __restrict__ THf1) {
    int tid = blockIdx.x * 256 + threadIdx.x;
    if (tid >= NCOL) return;
    int kk = tid / NCLASS, c = tid - kk * NCLASS;  // consecutive tid -> consecutive c
    const float* src = theta + kk * NCLASS + c;
    float v[DIM];
    float ss = 0.f;
    #pragma unroll
    for (int d = 0; d < DIM; ++d) {
        v[d] = src[(size_t)d * NCOL];
        ss += v[d] * v[d];
    }
    float sc = 1.0f / fmaxf(sqrtf(ss), 1e-12f);
    int j = c * KPROX + kk;
    int jt = j >> 4, jr = j & 15;
    #pragma unroll
    for (int h = 0; h < 8; ++h) {      // chunk h holds k = h*8 .. h*8+7
        unsigned short* dst = (h < 4 ? THf0 : THf1)
                            + ((size_t)jt * 64 + (h & 3) * 16 + jr) * 8;
        #pragma unroll
        for (int i = 0; i < 8; ++i)
            dst[i] = f32_to_bf16(v[h * 8 + i] * sc);
    }
}

// ---- main: MFMA GEMM + fused softmax, all loads coalesced, no barriers -----
__global__ __launch_bounds__(256)
void podnet_main(const unsigned short* __restrict__ Xf0,
                 const unsigned short* __restrict__ Xf1,
                 const unsigned short* __restrict__ THf0,
                 const unsigned short* __restrict__ THf1,
                 float* __restrict__ out) {
    __shared__ float S[4][BN][CSTR];   // 25.6 KB, wave-private slabs

    int bm = blockIdx.x / NBN, bn = blockIdx.x % NBN;
    int wave = threadIdx.x >> 6, lane = threadIdx.x & 63;

    const bf16x8* xf0 = (const bf16x8*)Xf0;
    const bf16x8* xf1 = (const bf16x8*)Xf1;
    const bf16x8* tf0 = (const bf16x8*)THf0;
    const bf16x8* tf1 = (const bf16x8*)THf1;

    int ab = (bm * 8 + wave * 2) * 64 + lane;   // 2 row-tiles per wave
    int bb = (bn * 5) * 64 + lane;              // 5 col-tiles per block

    bf16x8 a0[2], a1[2], b0[5], b1[5];          // 14 independent coalesced loads
    #pragma unroll
    for (int mt = 0; mt < 2; ++mt) { a0[mt] = xf0[ab + mt * 64]; a1[mt] = xf1[ab + mt * 64]; }
    #pragma unroll
    for (int t = 0; t < 5; ++t)    { b0[t]  = tf0[bb + t * 64];  b1[t]  = tf1[bb + t * 64]; }

    f32x4 acc[2][5];
    #pragma unroll
    for (int mt = 0; mt < 2; ++mt)
        #pragma unroll
        for (int t = 0; t < 5; ++t) {
            f32x4 c = {0.f, 0.f, 0.f, 0.f};
            c = __builtin_amdgcn_mfma_f32_16x16x32_bf16(a0[mt], b0[t], c, 0, 0, 0);
            c = __builtin_amdgcn_mfma_f32_16x16x32_bf16(a1[mt], b1[t], c, 0, 0, 0);
            acc[mt][t] = c;
        }

    int r16 = lane & 15, hi = lane >> 4;   // writer coords
    int rp  = lane >> 3, g  = lane & 7;    // reader coords: row-pair, class

    #pragma unroll
    for (int mt = 0; mt < 2; ++mt) {
        // scores -> col-major LDS: lane's 4 acc values are 4 consecutive rows
        // (bank-verified: each ds_write_b128 puts exactly 8 words on every bank)
        #pragma unroll
        for (int t = 0; t < 5; ++t) {
            f32x4 s;
            #pragma unroll
            for (int r = 0; r < 4; ++r)
                s[r] = fminf(2.f * acc[mt][t][r] - 2.f, 0.f);
            *(f32x4*)&S[wave][t * 16 + r16][hi * 4] = s;
        }
        // softmax over 10: lane owns (row-pair rp, class g); f32x2 reads
        float ps0 = 0.f, ws0 = 0.f, ps1 = 0.f, ws1 = 0.f;
        #pragma unroll
        for (int i = 0; i < KPROX; ++i) {
            f32x2 v = *(const f32x2*)&S[wave][g * 10 + i][rp * 2];
            float e0 = __expf(v.x), e1 = __expf(v.y);   // simi in [-4,0]: no max needed
            ps0 += e0; ws0 = fmaf(v.x, e0, ws0);
            ps1 += e1; ws1 = fmaf(v.y, e1, ws1);
        }
        size_t orow = (size_t)bm * BM + wave * 32 + mt * 16 + rp * 2;
        float* op = out + orow * NCLASS + bn * 8 + g;
        __builtin_nontemporal_store(ws0 / ps0, op);
        __builtin_nontemporal_store(ws1 / ps1, op + NCLASS);
    }
}

extern "C" void kernel_launch(void* const* d_in, const int* in_sizes, int n_in,
                              void* d_out, int out_size, void* d_ws, size_t ws_size,
                              hipStream_t stream) {
    const float* x     = (const float*)d_in[0];   // (8192, 64)
    const float* theta = (const float*)d_in[1];   // (64, 10, 1000)
    float* out = (float*)d_out;                   // (8192, 1000) f32

    unsigned short* Xf0 = (unsigned short*)d_ws;       // 512 KB each X plane
    unsigned short* Xf1 = Xf0 + (size_t)NBTILE * 512;
    unsigned short* Tf0 = Xf1 + (size_t)NBTILE * 512;  // 640 KB each TH plane
    unsigned short* Tf1 = Tf0 + (size_t)NNTILE * 512;

    norm_pack_x<<<NBTILE / 4, 256, 0, stream>>>(x, Xf0, Xf1);
    norm_pack_th<<<(NCOL + 255) / 256, 256, 0, stream>>>(theta, Tf0, Tf1);
    podnet_main<<<NBM * NBN, 256, 0, stream>>>(Xf0, Xf1, Tf0, Tf1, out);
}

// Round 4
// 42.473 us; speedup vs baseline: 2.4256x; 1.0038x over previous
//
#include <hip/hip_runtime.h>

// ---------------------------------------------------------------------------
// PodNetClassifier: out[b][c] = sum_k simi*softmax_k(simi),
//   simi[b,c,k] = -max(2 - 2*dot(a_b, th_{c*10+k}), 0)  (unit vectors)
// Round 4: exp2-based epilogue (log2e folded into LDS scores), rcp instead of
// f32 division, packed f32x2 softmax accumulation, rsq normalizers, merged
// prep kernel. GEMM structure unchanged from R3 (packed fragment planes,
// all-coalesced independent loads, wave-private LDS, no barriers).
// ---------------------------------------------------------------------------

#define BATCH   8192
#define DIM     64
#define KPROX   10
#define NCLASS  1000
#define NCOL    (NCLASS * KPROX)   // 10000
#define NBTILE  (BATCH / 16)       // 512
#define NNTILE  (NCOL / 16)        // 625

#define BM      128                // rows per block (4 waves x 32)
#define BN      80                 // cols per block (5 mfma tiles, 8 classes)
#define NBM     (BATCH / BM)       // 64
#define NBN     (NCOL / BN)        // 125
#define CSTR    20                 // LDS words per column slab (16 rows + pad)

#define XBLKS   (NBTILE / 4)       // 128 prep blocks for x
#define TBLKS   ((NCOL + 255) / 256) // 40 prep blocks for theta

typedef __attribute__((ext_vector_type(8))) short bf16x8;
typedef __attribute__((ext_vector_type(4))) float f32x4;
typedef __attribute__((ext_vector_type(2))) float f32x2;

#define LOG2E 1.4426950408889634f
#define LN2   0.6931471805599453f

__device__ inline unsigned short f32_to_bf16(float f) {
    unsigned int u = __float_as_uint(f);
    u += 0x7FFFu + ((u >> 16) & 1u);   // round-to-nearest-even
    return (unsigned short)(u >> 16);
}

// ---- merged prep: blocks [0,128) pack x, blocks [128,168) pack theta -------
// X planes: Xf_p[(bt*64 + lane)*8 + i] = a[bt*16 + (lane&15)][p*32 + (lane>>4)*8 + i]
// TH planes: same fragment layout over proxy rows j = c*10+kk.
__global__ __launch_bounds__(256)
void prep_kernel(const float* __restrict__ x, const float* __restrict__ theta,
                 unsigned short* __restrict__ Xf0, unsigned short* __restrict__ Xf1,
                 unsigned short* __restrict__ THf0, unsigned short* __restrict__ THf1) {
    if (blockIdx.x < XBLKS) {
        int wave = threadIdx.x >> 6, lane = threadIdx.x & 63;
        int bt  = blockIdx.x * 4 + wave;
        int r16 = lane & 15, hi = lane >> 4;
        const float* src = x + (size_t)(bt * 16 + r16) * DIM + hi * 8;
        f32x4 v0 = *(const f32x4*)(src);
        f32x4 v1 = *(const f32x4*)(src + 4);
        f32x4 v2 = *(const f32x4*)(src + 32);
        f32x4 v3 = *(const f32x4*)(src + 36);
        float ss = 0.f;
        #pragma unroll
        for (int i = 0; i < 4; ++i)
            ss += v0[i]*v0[i] + v1[i]*v1[i] + v2[i]*v2[i] + v3[i]*v3[i];
        ss += __shfl_xor(ss, 16);
        ss += __shfl_xor(ss, 32);
        float sc = __builtin_amdgcn_rsqf(ss);   // norms are O(8), no eps needed
        bf16x8 p0, p1;
        #pragma unroll
        for (int i = 0; i < 4; ++i) {
            p0[i]     = (short)f32_to_bf16(v0[i] * sc);
            p0[i + 4] = (short)f32_to_bf16(v1[i] * sc);
            p1[i]     = (short)f32_to_bf16(v2[i] * sc);
            p1[i + 4] = (short)f32_to_bf16(v3[i] * sc);
        }
        ((bf16x8*)Xf0)[bt * 64 + lane] = p0;
        ((bf16x8*)Xf1)[bt * 64 + lane] = p1;
    } else {
        int tid = (blockIdx.x - XBLKS) * 256 + threadIdx.x;
        if (tid >= NCOL) return;
        int kk = tid / NCLASS, c = tid - kk * NCLASS;  // consecutive tid -> consecutive c
        const float* src = theta + kk * NCLASS + c;
        float v[DIM];
        float ss = 0.f;
        #pragma unroll
        for (int d = 0; d < DIM; ++d) {
            v[d] = src[(size_t)d * NCOL];
            ss += v[d] * v[d];
        }
        float sc = __builtin_amdgcn_rsqf(ss);
        int j = c * KPROX + kk;
        int jt = j >> 4, jr = j & 15;
        #pragma unroll
        for (int h = 0; h < 8; ++h) {      // chunk h holds d = h*8 .. h*8+7
            unsigned short* dst = (h < 4 ? THf0 : THf1)
                                + ((size_t)jt * 64 + (h & 3) * 16 + jr) * 8;
            #pragma unroll
            for (int i = 0; i < 8; ++i)
                dst[i] = f32_to_bf16(v[h * 8 + i] * sc);
        }
    }
}

// ---- main: MFMA GEMM + fused softmax (exp2/rcp), no barriers ---------------
__global__ __launch_bounds__(256)
void podnet_main(const unsigned short* __restrict__ Xf0,
                 const unsigned short* __restrict__ Xf1,
                 const unsigned short* __restrict__ THf0,
                 const unsigned short* __restrict__ THf1,
                 float* __restrict__ out) {
    __shared__ float S[4][BN][CSTR];   // 25.6 KB, wave-private slabs

    int bm = blockIdx.x / NBN, bn = blockIdx.x % NBN;
    int wave = threadIdx.x >> 6, lane = threadIdx.x & 63;

    const bf16x8* xf0 = (const bf16x8*)Xf0;
    const bf16x8* xf1 = (const bf16x8*)Xf1;
    const bf16x8* tf0 = (const bf16x8*)THf0;
    const bf16x8* tf1 = (const bf16x8*)THf1;

    int ab = (bm * 8 + wave * 2) * 64 + lane;   // 2 row-tiles per wave
    int bb = (bn * 5) * 64 + lane;              // 5 col-tiles per block

    bf16x8 a0[2], a1[2], b0[5], b1[5];          // 14 independent coalesced loads
    #pragma unroll
    for (int mt = 0; mt < 2; ++mt) { a0[mt] = xf0[ab + mt * 64]; a1[mt] = xf1[ab + mt * 64]; }
    #pragma unroll
    for (int t = 0; t < 5; ++t)    { b0[t]  = tf0[bb + t * 64];  b1[t]  = tf1[bb + t * 64]; }

    f32x4 acc[2][5];
    #pragma unroll
    for (int mt = 0; mt < 2; ++mt)
        #pragma unroll
        for (int t = 0; t < 5; ++t) {
            f32x4 c = {0.f, 0.f, 0.f, 0.f};
            c = __builtin_amdgcn_mfma_f32_16x16x32_bf16(a0[mt], b0[t], c, 0, 0, 0);
            c = __builtin_amdgcn_mfma_f32_16x16x32_bf16(a1[mt], b1[t], c, 0, 0, 0);
            acc[mt][t] = c;
        }

    int r16 = lane & 15, hi = lane >> 4;   // writer coords
    int rp  = lane >> 3, g  = lane & 7;    // reader coords: row-pair, class

    #pragma unroll
    for (int mt = 0; mt < 2; ++mt) {
        // scores -> col-major LDS, pre-scaled by log2e:
        //   y = (2s-2)*log2e, clamped to <= 0   (simi = y*ln2, e^simi = 2^y)
        // bank check (per 16-lane HW phase): starts r16*20+hi*4 mod 32 -> 2-way, free
        #pragma unroll
        for (int t = 0; t < 5; ++t) {
            f32x4 s;
            #pragma unroll
            for (int r = 0; r < 4; ++r)
                s[r] = fminf(fmaf(acc[mt][t][r], 2.0f * LOG2E, -2.0f * LOG2E), 0.f);
            *(f32x4*)&S[wave][t * 16 + r16][hi * 4] = s;
        }
        // softmax over 10: lane owns (row-pair rp, class g); packed f32x2 math
        f32x2 ps = {0.f, 0.f}, ws = {0.f, 0.f};
        #pragma unroll
        for (int i = 0; i < KPROX; ++i) {
            f32x2 v = *(const f32x2*)&S[wave][g * 10 + i][rp * 2];
            f32x2 e;
            e.x = exp2f(v.x);              // y in [-5.77, 0]: no max pass needed
            e.y = exp2f(v.y);
            ps += e;
            ws += v * e;                   // sum y*2^y ; out = ln2 * ws/ps
        }
        float o0 = ws.x * __builtin_amdgcn_rcpf(ps.x) * LN2;
        float o1 = ws.y * __builtin_amdgcn_rcpf(ps.y) * LN2;
        size_t orow = (size_t)bm * BM + wave * 32 + mt * 16 + rp * 2;
        float* op = out + orow * NCLASS + bn * 8 + g;
        __builtin_nontemporal_store(o0, op);
        __builtin_nontemporal_store(o1, op + NCLASS);
    }
}

extern "C" void kernel_launch(void* const* d_in, const int* in_sizes, int n_in,
                              void* d_out, int out_size, void* d_ws, size_t ws_size,
                              hipStream_t stream) {
    const float* x     = (const float*)d_in[0];   // (8192, 64)
    const float* theta = (const float*)d_in[1];   // (64, 10, 1000)
    float* out = (float*)d_out;                   // (8192, 1000) f32

    unsigned short* Xf0 = (unsigned short*)d_ws;       // 512 KB each X plane
    unsigned short* Xf1 = Xf0 + (size_t)NBTILE * 512;
    unsigned short* Tf0 = Xf1 + (size_t)NBTILE * 512;  // 640 KB each TH plane
    unsigned short* Tf1 = Tf0 + (size_t)NNTILE * 512;

    prep_kernel<<<XBLKS + TBLKS, 256, 0, stream>>>(x, theta, Xf0, Xf1, Tf0, Tf1);
    podnet_main<<<NBM * NBN, 256, 0, stream>>>(Xf0, Xf1, Tf0, Tf1, out);
}

// Round 5
// 42.399 us; speedup vs baseline: 2.4299x; 1.0017x over previous
//
#include <hip/hip_runtime.h>

// ---------------------------------------------------------------------------
// PodNetClassifier: out[b][c] = sum_k simi*softmax_k(simi),
//   simi[b,c,k] = -max(2 - 2*dot(a_b, th_{c*10+k}), 0)  (unit vectors)
// Round 5: anti-serialization. launch_bounds(256,4) so the allocator may keep
// all 14 load results live (~96 regs needed); sched_barrier(0) pins all
// global loads before the MFMA block (1 latency window, not 14); epilogue
// interleaved (mt1 MFMAs cover mt0's LDS write latency).
// ---------------------------------------------------------------------------

#define BATCH   8192
#define DIM     64
#define KPROX   10
#define NCLASS  1000
#define NCOL    (NCLASS * KPROX)   // 10000
#define NBTILE  (BATCH / 16)       // 512
#define NNTILE  (NCOL / 16)        // 625

#define BM      128                // rows per block (4 waves x 32)
#define BN      80                 // cols per block (5 mfma tiles, 8 classes)
#define NBM     (BATCH / BM)       // 64
#define NBN     (NCOL / BN)        // 125
#define CSTR    20                 // LDS words per column slab (16 rows + pad)

#define XBLKS   (NBTILE / 4)         // 128 prep blocks for x
#define TBLKS   ((NCOL + 255) / 256) // 40 prep blocks for theta

typedef __attribute__((ext_vector_type(8))) short bf16x8;
typedef __attribute__((ext_vector_type(4))) float f32x4;
typedef __attribute__((ext_vector_type(2))) float f32x2;

#define LOG2E 1.4426950408889634f
#define LN2   0.6931471805599453f

__device__ inline unsigned short f32_to_bf16(float f) {
    unsigned int u = __float_as_uint(f);
    u += 0x7FFFu + ((u >> 16) & 1u);   // round-to-nearest-even
    return (unsigned short)(u >> 16);
}

// ---- merged prep: blocks [0,128) pack x, blocks [128,168) pack theta -------
// X planes: Xf_p[(bt*64 + lane)*8 + i] = a[bt*16 + (lane&15)][p*32 + (lane>>4)*8 + i]
// TH planes: same fragment layout over proxy rows j = c*10+kk.
__global__ __launch_bounds__(256)
void prep_kernel(const float* __restrict__ x, const float* __restrict__ theta,
                 unsigned short* __restrict__ Xf0, unsigned short* __restrict__ Xf1,
                 unsigned short* __restrict__ THf0, unsigned short* __restrict__ THf1) {
    if (blockIdx.x < XBLKS) {
        int wave = threadIdx.x >> 6, lane = threadIdx.x & 63;
        int bt  = blockIdx.x * 4 + wave;
        int r16 = lane & 15, hi = lane >> 4;
        const float* src = x + (size_t)(bt * 16 + r16) * DIM + hi * 8;
        f32x4 v0 = *(const f32x4*)(src);
        f32x4 v1 = *(const f32x4*)(src + 4);
        f32x4 v2 = *(const f32x4*)(src + 32);
        f32x4 v3 = *(const f32x4*)(src + 36);
        float ss = 0.f;
        #pragma unroll
        for (int i = 0; i < 4; ++i)
            ss += v0[i]*v0[i] + v1[i]*v1[i] + v2[i]*v2[i] + v3[i]*v3[i];
        ss += __shfl_xor(ss, 16);
        ss += __shfl_xor(ss, 32);
        float sc = __builtin_amdgcn_rsqf(ss);   // norms are O(8), no eps needed
        bf16x8 p0, p1;
        #pragma unroll
        for (int i = 0; i < 4; ++i) {
            p0[i]     = (short)f32_to_bf16(v0[i] * sc);
            p0[i + 4] = (short)f32_to_bf16(v1[i] * sc);
            p1[i]     = (short)f32_to_bf16(v2[i] * sc);
            p1[i + 4] = (short)f32_to_bf16(v3[i] * sc);
        }
        ((bf16x8*)Xf0)[bt * 64 + lane] = p0;
        ((bf16x8*)Xf1)[bt * 64 + lane] = p1;
    } else {
        int tid = (blockIdx.x - XBLKS) * 256 + threadIdx.x;
        if (tid >= NCOL) return;
        int kk = tid / NCLASS, c = tid - kk * NCLASS;  // consecutive tid -> consecutive c
        const float* src = theta + kk * NCLASS + c;
        float v[DIM];
        float ss = 0.f;
        #pragma unroll
        for (int d = 0; d < DIM; ++d) {
            v[d] = src[(size_t)d * NCOL];
            ss += v[d] * v[d];
        }
        float sc = __builtin_amdgcn_rsqf(ss);
        int j = c * KPROX + kk;
        int jt = j >> 4, jr = j & 15;
        #pragma unroll
        for (int h = 0; h < 8; ++h) {      // chunk h holds d = h*8 .. h*8+7
            unsigned short* dst = (h < 4 ? THf0 : THf1)
                                + ((size_t)jt * 64 + (h & 3) * 16 + jr) * 8;
            #pragma unroll
            for (int i = 0; i < 8; ++i)
                dst[i] = f32_to_bf16(v[h * 8 + i] * sc);
        }
    }
}

// ---- main: MFMA GEMM + fused softmax, loads pinned ahead of compute --------
__global__ __launch_bounds__(256, 4)   // cap 128 VGPR: 4 waves/SIMD, loads stay live
void podnet_main(const unsigned short* __restrict__ Xf0,
                 const unsigned short* __restrict__ Xf1,
                 const unsigned short* __restrict__ THf0,
                 const unsigned short* __restrict__ THf1,
                 float* __restrict__ out) {
    __shared__ float S[4][BN][CSTR];   // 25.6 KB, wave-private slabs

    int bm = blockIdx.x / NBN, bn = blockIdx.x % NBN;
    int wave = threadIdx.x >> 6, lane = threadIdx.x & 63;

    const bf16x8* xf0 = (const bf16x8*)Xf0;
    const bf16x8* xf1 = (const bf16x8*)Xf1;
    const bf16x8* tf0 = (const bf16x8*)THf0;
    const bf16x8* tf1 = (const bf16x8*)THf1;

    int ab = (bm * 8 + wave * 2) * 64 + lane;   // 2 row-tiles per wave
    int bb = (bn * 5) * 64 + lane;              // 5 col-tiles per block

    // ---- all 14 loads issued back-to-back, pinned before any compute ------
    bf16x8 a00 = xf0[ab];       bf16x8 a01 = xf1[ab];
    bf16x8 a10 = xf0[ab + 64];  bf16x8 a11 = xf1[ab + 64];
    bf16x8 b0[5], b1[5];
    #pragma unroll
    for (int t = 0; t < 5; ++t) { b0[t] = tf0[bb + t * 64]; b1[t] = tf1[bb + t * 64]; }
    __builtin_amdgcn_sched_barrier(0);          // nothing crosses: loads stay up front

    int r16 = lane & 15, hi = lane >> 4;   // writer coords
    int rp  = lane >> 3, g  = lane & 7;    // reader coords: row-pair, class

    // ---- mt0 MFMAs ---------------------------------------------------------
    f32x4 acc0[5];
    #pragma unroll
    for (int t = 0; t < 5; ++t) {
        f32x4 c = {0.f, 0.f, 0.f, 0.f};
        c = __builtin_amdgcn_mfma_f32_16x16x32_bf16(a00, b0[t], c, 0, 0, 0);
        c = __builtin_amdgcn_mfma_f32_16x16x32_bf16(a01, b1[t], c, 0, 0, 0);
        acc0[t] = c;
    }
    // mt0 scores -> LDS, pre-scaled by log2e: y = (2s-2)*log2e, y <= 0
    #pragma unroll
    for (int t = 0; t < 5; ++t) {
        f32x4 s;
        #pragma unroll
        for (int r = 0; r < 4; ++r)
            s[r] = fminf(fmaf(acc0[t][r], 2.0f * LOG2E, -2.0f * LOG2E), 0.f);
        *(f32x4*)&S[wave][t * 16 + r16][hi * 4] = s;
    }

    // ---- mt1 MFMAs (cover mt0's LDS write latency) -------------------------
    f32x4 acc1[5];
    #pragma unroll
    for (int t = 0; t < 5; ++t) {
        f32x4 c = {0.f, 0.f, 0.f, 0.f};
        c = __builtin_amdgcn_mfma_f32_16x16x32_bf16(a10, b0[t], c, 0, 0, 0);
        c = __builtin_amdgcn_mfma_f32_16x16x32_bf16(a11, b1[t], c, 0, 0, 0);
        acc1[t] = c;
    }

    // ---- mt0 softmax over 10 (lane owns row-pair rp, class g) --------------
    {
        f32x2 ps = {0.f, 0.f}, ws = {0.f, 0.f};
        #pragma unroll
        for (int i = 0; i < KPROX; ++i) {
            f32x2 v = *(const f32x2*)&S[wave][g * 10 + i][rp * 2];
            f32x2 e; e.x = exp2f(v.x); e.y = exp2f(v.y);  // y in [-5.77,0]
            ps += e;
            ws += v * e;
        }
        float o0 = ws.x * __builtin_amdgcn_rcpf(ps.x) * LN2;
        float o1 = ws.y * __builtin_amdgcn_rcpf(ps.y) * LN2;
        size_t orow = (size_t)bm * BM + wave * 32 + rp * 2;
        float* op = out + orow * NCLASS + bn * 8 + g;
        __builtin_nontemporal_store(o0, op);
        __builtin_nontemporal_store(o1, op + NCLASS);
    }

    // ---- mt1 scores -> LDS (same slab; per-wave LDS is in-order, safe) -----
    #pragma unroll
    for (int t = 0; t < 5; ++t) {
        f32x4 s;
        #pragma unroll
        for (int r = 0; r < 4; ++r)
            s[r] = fminf(fmaf(acc1[t][r], 2.0f * LOG2E, -2.0f * LOG2E), 0.f);
        *(f32x4*)&S[wave][t * 16 + r16][hi * 4] = s;
    }
    // ---- mt1 softmax --------------------------------------------------------
    {
        f32x2 ps = {0.f, 0.f}, ws = {0.f, 0.f};
        #pragma unroll
        for (int i = 0; i < KPROX; ++i) {
            f32x2 v = *(const f32x2*)&S[wave][g * 10 + i][rp * 2];
            f32x2 e; e.x = exp2f(v.x); e.y = exp2f(v.y);
            ps += e;
            ws += v * e;
        }
        float o0 = ws.x * __builtin_amdgcn_rcpf(ps.x) * LN2;
        float o1 = ws.y * __builtin_amdgcn_rcpf(ps.y) * LN2;
        size_t orow = (size_t)bm * BM + wave * 32 + 16 + rp * 2;
        float* op = out + orow * NCLASS + bn * 8 + g;
        __builtin_nontemporal_store(o0, op);
        __builtin_nontemporal_store(o1, op + NCLASS);
    }
}

extern "C" void kernel_launch(void* const* d_in, const int* in_sizes, int n_in,
                              void* d_out, int out_size, void* d_ws, size_t ws_size,
                              hipStream_t stream) {
    const float* x     = (const float*)d_in[0];   // (8192, 64)
    const float* theta = (const float*)d_in[1];   // (64, 10, 1000)
    float* out = (float*)d_out;                   // (8192, 1000) f32

    unsigned short* Xf0 = (unsigned short*)d_ws;       // 512 KB each X plane
    unsigned short* Xf1 = Xf0 + (size_t)NBTILE * 512;
    unsigned short* Tf0 = Xf1 + (size_t)NBTILE * 512;  // 640 KB each TH plane
    unsigned short* Tf1 = Tf0 + (size_t)NNTILE * 512;

    prep_kernel<<<XBLKS + TBLKS, 256, 0, stream>>>(x, theta, Xf0, Xf1, Tf0, Tf1);
    podnet_main<<<NBM * NBN, 256, 0, stream>>>(Xf0, Xf1, Tf0, Tf1, out);
}

// Round 6
// 41.797 us; speedup vs baseline: 2.4649x; 1.0144x over previous
//
#include <hip/hip_runtime.h>

// ---------------------------------------------------------------------------
// PodNetClassifier: out[b][c] = sum_k simi*softmax_k(simi),
//   simi[b,c,k] = -max(2 - 2*dot(a_b, th_{c*10+k}), 0)  (unit vectors)
// Round 6: wave tile 32x80 -> 64x80 (BM=256). Halves register-fill L1 traffic
// (5.6 -> 3.6 B/output) and halves wave count; B fragments amortized over 4
// row-tiles. mt-pipelined: mfma(k+1) covers wr(k)'s LDS latency; acc held one
// mt at a time (~130 VGPR). Epilogue math unchanged (exp2/rcp, f32 LDS).
// ---------------------------------------------------------------------------

#define BATCH   8192
#define DIM     64
#define KPROX   10
#define NCLASS  1000
#define NCOL    (NCLASS * KPROX)   // 10000
#define NBTILE  (BATCH / 16)       // 512
#define NNTILE  (NCOL / 16)        // 625

#define BM      256                // rows per block (4 waves x 64)
#define BN      80                 // cols per block (5 mfma tiles, 8 classes)
#define NBM     (BATCH / BM)       // 32
#define NBN     (NCOL / BN)        // 125
#define CSTR    20                 // LDS words per column slab (16 rows + pad)

#define XBLKS   (NBTILE / 4)         // 128 prep blocks for x
#define TBLKS   ((NCOL + 255) / 256) // 40 prep blocks for theta

typedef __attribute__((ext_vector_type(8))) short bf16x8;
typedef __attribute__((ext_vector_type(4))) float f32x4;
typedef __attribute__((ext_vector_type(2))) float f32x2;

#define LOG2E 1.4426950408889634f
#define LN2   0.6931471805599453f

__device__ inline unsigned short f32_to_bf16(float f) {
    unsigned int u = __float_as_uint(f);
    u += 0x7FFFu + ((u >> 16) & 1u);   // round-to-nearest-even
    return (unsigned short)(u >> 16);
}

// ---- merged prep: blocks [0,128) pack x, blocks [128,168) pack theta -------
// X planes: Xf_p[(bt*64 + lane)*8 + i] = a[bt*16 + (lane&15)][p*32 + (lane>>4)*8 + i]
// TH planes: same fragment layout over proxy rows j = c*10+kk.
__global__ __launch_bounds__(256)
void prep_kernel(const float* __restrict__ x, const float* __restrict__ theta,
                 unsigned short* __restrict__ Xf0, unsigned short* __restrict__ Xf1,
                 unsigned short* __restrict__ THf0, unsigned short* __restrict__ THf1) {
    if (blockIdx.x < XBLKS) {
        int wave = threadIdx.x >> 6, lane = threadIdx.x & 63;
        int bt  = blockIdx.x * 4 + wave;
        int r16 = lane & 15, hi = lane >> 4;
        const float* src = x + (size_t)(bt * 16 + r16) * DIM + hi * 8;
        f32x4 v0 = *(const f32x4*)(src);
        f32x4 v1 = *(const f32x4*)(src + 4);
        f32x4 v2 = *(const f32x4*)(src + 32);
        f32x4 v3 = *(const f32x4*)(src + 36);
        float ss = 0.f;
        #pragma unroll
        for (int i = 0; i < 4; ++i)
            ss += v0[i]*v0[i] + v1[i]*v1[i] + v2[i]*v2[i] + v3[i]*v3[i];
        ss += __shfl_xor(ss, 16);
        ss += __shfl_xor(ss, 32);
        float sc = __builtin_amdgcn_rsqf(ss);   // norms are O(8), no eps needed
        bf16x8 p0, p1;
        #pragma unroll
        for (int i = 0; i < 4; ++i) {
            p0[i]     = (short)f32_to_bf16(v0[i] * sc);
            p0[i + 4] = (short)f32_to_bf16(v1[i] * sc);
            p1[i]     = (short)f32_to_bf16(v2[i] * sc);
            p1[i + 4] = (short)f32_to_bf16(v3[i] * sc);
        }
        ((bf16x8*)Xf0)[bt * 64 + lane] = p0;
        ((bf16x8*)Xf1)[bt * 64 + lane] = p1;
    } else {
        int tid = (blockIdx.x - XBLKS) * 256 + threadIdx.x;
        if (tid >= NCOL) return;
        int kk = tid / NCLASS, c = tid - kk * NCLASS;  // consecutive tid -> consecutive c
        const float* src = theta + kk * NCLASS + c;
        float v[DIM];
        float ss = 0.f;
        #pragma unroll
        for (int d = 0; d < DIM; ++d) {
            v[d] = src[(size_t)d * NCOL];
            ss += v[d] * v[d];
        }
        float sc = __builtin_amdgcn_rsqf(ss);
        int j = c * KPROX + kk;
        int jt = j >> 4, jr = j & 15;
        #pragma unroll
        for (int h = 0; h < 8; ++h) {      // chunk h holds d = h*8 .. h*8+7
            unsigned short* dst = (h < 4 ? THf0 : THf1)
                                + ((size_t)jt * 64 + (h & 3) * 16 + jr) * 8;
            #pragma unroll
            for (int i = 0; i < 8; ++i)
                dst[i] = f32_to_bf16(v[h * 8 + i] * sc);
        }
    }
}

// ---- main: 64x80 wave tiles, mt-pipelined MFMA + fused softmax -------------
__global__ __launch_bounds__(256, 3)
void podnet_main(const unsigned short* __restrict__ Xf0,
                 const unsigned short* __restrict__ Xf1,
                 const unsigned short* __restrict__ THf0,
                 const unsigned short* __restrict__ THf1,
                 float* __restrict__ out) {
    __shared__ float S[4][BN][CSTR];   // 25.6 KB, wave-private slabs

    int bm = blockIdx.x / NBN, bn = blockIdx.x % NBN;
    int wave = threadIdx.x >> 6, lane = threadIdx.x & 63;

    const bf16x8* xf0 = (const bf16x8*)Xf0;
    const bf16x8* xf1 = (const bf16x8*)Xf1;
    const bf16x8* tf0 = (const bf16x8*)THf0;
    const bf16x8* tf1 = (const bf16x8*)THf1;

    int ab = (bm * 16 + wave * 4) * 64 + lane;  // 4 row-tiles per wave
    int bb = (bn * 5) * 64 + lane;              // 5 col-tiles per block

    // ---- all 18 loads issued back-to-back, pinned before any compute ------
    bf16x8 a0[4], a1[4], b0[5], b1[5];
    #pragma unroll
    for (int k = 0; k < 4; ++k) { a0[k] = xf0[ab + k * 64]; a1[k] = xf1[ab + k * 64]; }
    #pragma unroll
    for (int t = 0; t < 5; ++t) { b0[t] = tf0[bb + t * 64]; b1[t] = tf1[bb + t * 64]; }
    __builtin_amdgcn_sched_barrier(0);

    int r16 = lane & 15, hi = lane >> 4;   // writer coords
    int rp  = lane >> 3, g  = lane & 7;    // reader coords: row-pair, class

    size_t orow_base = (size_t)bm * BM + wave * 64 + rp * 2;
    float* obase = out + bn * 8 + g;

    // mt=0 MFMAs
    f32x4 acc_c[5], acc_n[5];
    #pragma unroll
    for (int t = 0; t < 5; ++t) {
        f32x4 c = {0.f, 0.f, 0.f, 0.f};
        c = __builtin_amdgcn_mfma_f32_16x16x32_bf16(a0[0], b0[t], c, 0, 0, 0);
        c = __builtin_amdgcn_mfma_f32_16x16x32_bf16(a1[0], b1[t], c, 0, 0, 0);
        acc_c[t] = c;
    }

    #pragma unroll
    for (int k = 0; k < 4; ++k) {
        // scores(k) -> LDS, pre-scaled by log2e: y = (2s-2)*log2e, y <= 0
        #pragma unroll
        for (int t = 0; t < 5; ++t) {
            f32x4 s;
            #pragma unroll
            for (int r = 0; r < 4; ++r)
                s[r] = fminf(fmaf(acc_c[t][r], 2.0f * LOG2E, -2.0f * LOG2E), 0.f);
            *(f32x4*)&S[wave][t * 16 + r16][hi * 4] = s;
        }
        // next mt's MFMAs cover the LDS write latency
        if (k < 3) {
            #pragma unroll
            for (int t = 0; t < 5; ++t) {
                f32x4 c = {0.f, 0.f, 0.f, 0.f};
                c = __builtin_amdgcn_mfma_f32_16x16x32_bf16(a0[k + 1], b0[t], c, 0, 0, 0);
                c = __builtin_amdgcn_mfma_f32_16x16x32_bf16(a1[k + 1], b1[t], c, 0, 0, 0);
                acc_n[t] = c;
            }
        }
        // softmax over 10: lane owns (row-pair rp, class g); packed f32x2 math
        {
            f32x2 ps = {0.f, 0.f}, ws = {0.f, 0.f};
            #pragma unroll
            for (int i = 0; i < KPROX; ++i) {
                f32x2 v = *(const f32x2*)&S[wave][g * 10 + i][rp * 2];
                f32x2 e; e.x = exp2f(v.x); e.y = exp2f(v.y);  // y in [-5.77,0]
                ps += e;
                ws += v * e;
            }
            float o0 = ws.x * __builtin_amdgcn_rcpf(ps.x) * LN2;
            float o1 = ws.y * __builtin_amdgcn_rcpf(ps.y) * LN2;
            float* op = obase + (orow_base + k * 16) * NCLASS;
            __builtin_nontemporal_store(o0, op);
            __builtin_nontemporal_store(o1, op + NCLASS);
        }
        #pragma unroll
        for (int t = 0; t < 5; ++t) acc_c[t] = acc_n[t];
    }
}

extern "C" void kernel_launch(void* const* d_in, const int* in_sizes, int n_in,
                              void* d_out, int out_size, void* d_ws, size_t ws_size,
                              hipStream_t stream) {
    const float* x     = (const float*)d_in[0];   // (8192, 64)
    const float* theta = (const float*)d_in[1];   // (64, 10, 1000)
    float* out = (float*)d_out;                   // (8192, 1000) f32

    unsigned short* Xf0 = (unsigned short*)d_ws;       // 512 KB each X plane
    unsigned short* Xf1 = Xf0 + (size_t)NBTILE * 512;
    unsigned short* Tf0 = Xf1 + (size_t)NBTILE * 512;  // 640 KB each TH plane
    unsigned short* Tf1 = Tf0 + (size_t)NNTILE * 512;

    prep_kernel<<<XBLKS + TBLKS, 256, 0, stream>>>(x, theta, Xf0, Xf1, Tf0, Tf1);
    podnet_main<<<NBM * NBN, 256, 0, stream>>>(Xf0, Xf1, Tf0, Tf1, out);
}